// Round 6
// baseline (83.697 us; speedup 1.0000x reference)
//
#include <hip/hip_runtime.h>
#include <math.h>

#define E_THREADS 128
#define EPB 128   // edges per block

typedef __attribute__((ext_vector_type(8))) short short8;
typedef __attribute__((ext_vector_type(4))) float floatx4;

// ws layout:
//   [0,     16384)  WF  : 1024 x uint4 — per-lane MFMA A-fragments (8 bf16 each)
//                         entry (u*2+s)*64 + lane holds W'[n=16u+(lane&15)][k=s*32+(lane>>4)*8 ..+8]
//                         (k==60 row = LN-folded bias; k>60 = 0)
//   [16384, 16896)  W2A : 128 floats — layer-2 weight (head col 0) for fused neuron n
//   [16896, 17024)  W2B : 32 floats  — routing col-1 weights for n=96..127
//   [17024, 17040)  SC  : 4 floats   — bn2, be2, br2[0], br2[1]

// A = 1.125*log2(e) = 1.6230319
#define A_L2E 1.6230319f

__device__ inline unsigned short f2bf(float f) {
    union { float f; unsigned u; } v; v.f = f;
    unsigned r = v.u + 0x7FFFu + ((v.u >> 16) & 1u);
    return (unsigned short)(r >> 16);
}

__device__ inline unsigned cvt_pk_bf16(float lo, float hi) {
    unsigned r;
    asm("v_cvt_pk_bf16_f32 %0, %1, %2" : "=v"(r) : "v"(lo), "v"(hi));
    return r;
}

__device__ inline float fexp2(float x) { return __builtin_amdgcn_exp2f(x); }
__device__ inline float frcp(float x)  { return __builtin_amdgcn_rcpf(x); }
#define LOG2E 1.44269504f

__global__ __launch_bounds__(256)
void prep_weights(
    const float* __restrict__ ln_g, const float* __restrict__ ln_b,
    const float* __restrict__ wn1, const float* __restrict__ bn1,
    const float* __restrict__ wn2, const float* __restrict__ bn2,
    const float* __restrict__ we1, const float* __restrict__ be1,
    const float* __restrict__ we2, const float* __restrict__ be2,
    const float* __restrict__ wr1, const float* __restrict__ br1,
    const float* __restrict__ wr2, const float* __restrict__ br2,
    char* __restrict__ ws)
{
    uint4* WF  = (uint4*)ws;
    float* W2A = (float*)(ws + 16384);
    float* W2B = (float*)(ws + 16896);
    float* SC  = (float*)(ws + 17024);
    const int tid = threadIdx.x;

    // ---- A fragments (LN affine folded: W' = g*W, bias row = b1 + W^T b_ln) ----
    for (int idx = tid; idx < 1024; idx += 256) {
        int u = idx >> 7, s = (idx >> 6) & 1, lane = idx & 63;
        int lcol = lane & 15, khi = lane >> 4;
        int n = 16 * u + lcol;
        int kbase = s * 32 + khi * 8;
        float w8[8];
        for (int j = 0; j < 8; ++j) {
            int k = kbase + j;
            float w = 0.0f;
            if (k < 60) {
                float wv = (n < 32) ? wn1[k * 32 + n]
                         : (n < 96) ? we1[k * 64 + (n - 32)]
                                    : wr1[k * 32 + (n - 96)];
                w = ln_g[k] * wv;
            } else if (k == 60) {
                float b = (n < 32) ? bn1[n] : (n < 96) ? be1[n - 32] : br1[n - 96];
                for (int kk = 0; kk < 60; ++kk) {
                    float wv = (n < 32) ? wn1[kk * 32 + n]
                             : (n < 96) ? we1[kk * 64 + (n - 32)]
                                        : wr1[kk * 32 + (n - 96)];
                    b += ln_b[kk] * wv;
                }
                w = b;
            }
            w8[j] = w;
        }
        unsigned q0 = (unsigned)f2bf(w8[0]) | ((unsigned)f2bf(w8[1]) << 16);
        unsigned q1 = (unsigned)f2bf(w8[2]) | ((unsigned)f2bf(w8[3]) << 16);
        unsigned q2 = (unsigned)f2bf(w8[4]) | ((unsigned)f2bf(w8[5]) << 16);
        unsigned q3 = (unsigned)f2bf(w8[6]) | ((unsigned)f2bf(w8[7]) << 16);
        WF[idx] = make_uint4(q0, q1, q2, q3);
    }
    // ---- layer-2 weights, plain layout ----
    if (tid < 128) {
        int n = tid;
        W2A[n] = (n < 32) ? wn2[n] : (n < 96) ? we2[n - 32] : wr2[(n - 96) * 2];
    }
    if (tid >= 128 && tid < 160) W2B[tid - 128] = wr2[(tid - 128) * 2 + 1];
    if (tid == 0) { SC[0] = bn2[0]; SC[1] = be2[0]; SC[2] = br2[0]; SC[3] = br2[1]; }
}

__attribute__((amdgpu_waves_per_eu(4, 5)))
__global__ __launch_bounds__(E_THREADS, 4)
void exchange_block_kernel(
    const int*   __restrict__ edge_src,
    const int*   __restrict__ edge_dst,
    const int*   __restrict__ batch_idx,
    const float* __restrict__ cell,
    const float* __restrict__ edge_shift,
    const float* __restrict__ pos,
    const float* __restrict__ angles,
    const float* __restrict__ cr_bonds,
    const char*  __restrict__ ws,
    float* __restrict__ out, int E)
{
    __shared__ __align__(16) unsigned short HLDS[EPB * 64];   // 16384 B
    __shared__ __align__(16) float LW2A[128];                 // 512 B
    __shared__ __align__(16) float LW2B[32];                  // 128 B

    const int tid = threadIdx.x;
    const int e = blockIdx.x * EPB + tid;

    // stage tiny layer-2 tables
    LW2A[tid] = ((const float*)(ws + 16384))[tid];
    if (tid < 32) LW2B[tid] = ((const float*)(ws + 16896))[tid];

    // ---- phase 1: RBF (geometric recurrence) + LayerNorm (affine folded) ----
    float h[64];
    if (e < E) {
        int s = edge_src[e];
        int d = edge_dst[e];
        int g = batch_idx[s];
        float sh0 = edge_shift[e * 3 + 0];
        float sh1 = edge_shift[e * 3 + 1];
        float sh2 = edge_shift[e * 3 + 2];
        const float* c = cell + g * 9;
        float t0 = sh0 * c[0] + sh1 * c[3] + sh2 * c[6];
        float t1 = sh0 * c[1] + sh1 * c[4] + sh2 * c[7];
        float t2 = sh0 * c[2] + sh1 * c[5] + sh2 * c[8];
        float r0 = pos[d * 3 + 0] - pos[s * 3 + 0] + t0;
        float r1 = pos[d * 3 + 1] - pos[s * 3 + 1] + t1;
        float r2 = pos[d * 3 + 2] - pos[s * 3 + 2] + t2;
        float dist = sqrtf(r0 * r0 + r1 * r1 + r2 * r2);

        float z[6];
        z[0] = (dist - 4.0f) * (1.0f / 0.16f);
        z[1] = (angles[e] + 0.025f) * (1.0f / 0.06f);
        z[2] = (cr_bonds[e * 4 + 0] - 2.8f) * (1.0f / 0.035f);
        z[3] = (cr_bonds[e * 4 + 1] - 2.8f) * (1.0f / 0.035f);
        z[4] = (cr_bonds[e * 4 + 2] - 2.8f) * (1.0f / 0.035f);
        z[5] = (cr_bonds[e * 4 + 3] - 2.8f) * (1.0f / 0.035f);

        // h_k = exp2(-A(z-o_k)^2); h_{k+1} = h_k * r_k, r_{k+1} = r_k * (1/e)
        #pragma unroll
        for (int gi = 0; gi < 6; ++gi) {
            float zv = fminf(13.0f, fmaxf(-13.0f, z[gi]));
            float tt = zv + 3.0f;
            float hv = fexp2(-A_L2E * tt * tt);
            float rv = fexp2(fmaf(zv, 2.1640426f, 5.7707802f));
            h[gi * 10] = hv;
            #pragma unroll
            for (int k = 1; k < 10; ++k) {
                hv *= rv;
                rv *= 0.36787944f;   // 1/e
                h[gi * 10 + k] = hv;
            }
        }
        float mu = 0.0f;
        #pragma unroll
        for (int k = 0; k < 60; ++k) mu += h[k];
        mu *= (1.0f / 60.0f);
        float var = 0.0f;
        #pragma unroll
        for (int k = 0; k < 60; ++k) { float xc = h[k] - mu; var += xc * xc; }
        var *= (1.0f / 60.0f);
        float rs = rsqrtf(var + 1e-5f);
        float nmurs = -mu * rs;
        #pragma unroll
        for (int k = 0; k < 60; ++k) h[k] = fmaf(h[k], rs, nmurs);
    } else {
        #pragma unroll
        for (int k = 0; k < 60; ++k) h[k] = 0.0f;
    }
    h[60] = 1.0f;   // bias column
    h[61] = 0.0f; h[62] = 0.0f; h[63] = 0.0f;

    {
        const int swz = (tid & 7) << 4;
        #pragma unroll
        for (int c = 0; c < 8; ++c) {
            unsigned q0 = cvt_pk_bf16(h[8 * c + 0], h[8 * c + 1]);
            unsigned q1 = cvt_pk_bf16(h[8 * c + 2], h[8 * c + 3]);
            unsigned q2 = cvt_pk_bf16(h[8 * c + 4], h[8 * c + 5]);
            unsigned q3 = cvt_pk_bf16(h[8 * c + 6], h[8 * c + 7]);
            *(uint4*)((char*)HLDS + tid * 128 + ((c * 16) ^ swz)) = make_uint4(q0, q1, q2, q3);
        }
    }
    __syncthreads();

    // ---- phase 2: MFMA  C[n][edge] = W'[n][k] * H^T[k][edge] + fused epilogue ----
    const uint4* WF = (const uint4*)ws;
    const float* SC = (const float*)(ws + 17024);

    const int lane = tid & 63;
    const int wv   = tid >> 6;
    const int lcol = lane & 15;
    const int khi  = lane >> 4;
    const int kof  = khi * 16;

    // weight fragments: load once, pin in registers (h[] is dead now)
    uint4 wf[16];
    #pragma unroll
    for (int i = 0; i < 16; ++i) wf[i] = WF[i * 64 + lane];
    #pragma unroll
    for (int i = 0; i < 16; ++i)
        asm volatile("" : "+v"(wf[i].x), "+v"(wf[i].y), "+v"(wf[i].z), "+v"(wf[i].w));

    const float bn2v = SC[0], be2v = SC[1], br2v0 = SC[2], br2v1 = SC[3];

    #pragma unroll
    for (int t = 0; t < 4; ++t) {
        const int hrow = wv * 64 + t * 16 + lcol;
        const char* hbase = (const char*)HLDS + hrow * 128;
        const int hswz = (hrow & 7) << 4;
        short8 b0 = *(const short8*)(hbase + ((0  + kof) ^ hswz));
        short8 b1 = *(const short8*)(hbase + ((64 + kof) ^ hswz));

        float sN = 0.0f, sE = 0.0f, sR0 = 0.0f, sR1 = 0.0f;
        #pragma unroll
        for (int u = 0; u < 8; ++u) {
            short8 a0 = *(const short8*)&wf[u * 2 + 0];
            short8 a1 = *(const short8*)&wf[u * 2 + 1];
            floatx4 acc = (floatx4){0.0f, 0.0f, 0.0f, 0.0f};
            acc = __builtin_amdgcn_mfma_f32_16x16x32_bf16(a0, b0, acc, 0, 0, 0);
            acc = __builtin_amdgcn_mfma_f32_16x16x32_bf16(a1, b1, acc, 0, 0, 0);

            // broadcast reads: all 16 lanes of a khi-group hit the same float4
            float4 w2 = *(const float4*)&LW2A[16 * u + khi * 4];
            const float* w2p = (const float*)&w2;
            float4 wb4;
            const float* wbp = (const float*)&wb4;
            if (u >= 6) wb4 = *(const float4*)&LW2B[(u - 6) * 16 + khi * 4];
            #pragma unroll
            for (int j = 0; j < 4; ++j) {
                float a  = acc[j];
                float sl = a * frcp(1.0f + fexp2(a * -LOG2E));
                float w  = w2p[j];
                if (u < 2)      sN += sl * w;
                else if (u < 6) sE += sl * w;
                else {
                    sR0 += sl * w;
                    sR1 += sl * wbp[j];
                }
            }
        }
        // reduce across the 4 khi groups
        sN  += __shfl_xor(sN,  16); sN  += __shfl_xor(sN,  32);
        sE  += __shfl_xor(sE,  16); sE  += __shfl_xor(sE,  32);
        sR0 += __shfl_xor(sR0, 16); sR0 += __shfl_xor(sR0, 32);
        sR1 += __shfl_xor(sR1, 16); sR1 += __shfl_xor(sR1, 32);

        sN += bn2v; sE += be2v; sR0 += br2v0; sR1 += br2v1;
        float rt = frcp(1.0f + fexp2((sR1 - sR0) * LOG2E));   // sigmoid(sR0-sR1)
        float val = sE + rt * (sN - sE);

        if (lane < 16) {
            int eb = blockIdx.x * EPB + wv * 64 + t * 16 + lcol;
            if (eb < E) out[eb] = val;
        }
    }
}

extern "C" void kernel_launch(void* const* d_in, const int* in_sizes, int n_in,
                              void* d_out, int out_size, void* d_ws, size_t ws_size,
                              hipStream_t stream)
{
    const int*   edge_src  = (const int*)  d_in[0];
    const int*   edge_dst  = (const int*)  d_in[1];
    const int*   batch_idx = (const int*)  d_in[2];
    const float* cell      = (const float*)d_in[3];
    const float* edge_shift= (const float*)d_in[4];
    const float* pos       = (const float*)d_in[5];
    const float* angles    = (const float*)d_in[6];
    const float* cr_bonds  = (const float*)d_in[7];
    const float* ln_g      = (const float*)d_in[8];
    const float* ln_b      = (const float*)d_in[9];
    const float* wn1 = (const float*)d_in[10]; const float* bn1 = (const float*)d_in[11];
    const float* wn2 = (const float*)d_in[12]; const float* bn2 = (const float*)d_in[13];
    const float* we1 = (const float*)d_in[14]; const float* be1 = (const float*)d_in[15];
    const float* we2 = (const float*)d_in[16]; const float* be2 = (const float*)d_in[17];
    const float* wr1 = (const float*)d_in[18]; const float* br1 = (const float*)d_in[19];
    const float* wr2 = (const float*)d_in[20]; const float* br2 = (const float*)d_in[21];

    int E = in_sizes[0];
    float* out = (float*)d_out;

    hipLaunchKernelGGL(prep_weights, dim3(1), dim3(256), 0, stream,
                       ln_g, ln_b, wn1, bn1, wn2, bn2, we1, be1, we2, be2,
                       wr1, br1, wr2, br2, (char*)d_ws);

    int grid = (E + EPB - 1) / EPB;
    hipLaunchKernelGGL(exchange_block_kernel, dim3(grid), dim3(E_THREADS), 0, stream,
                       edge_src, edge_dst, batch_idx, cell, edge_shift, pos,
                       angles, cr_bonds, (const char*)d_ws, out, E);
}